// Round 7
// baseline (1419.640 us; speedup 1.0000x reference)
//
#include <hip/hip_runtime.h>
#include <hip/hip_bf16.h>

constexpr int D        = 128;   // feature dim = K = UNITS
constexpr int BM       = 64;    // nodes per block in GEMM
constexpr int CHUNK    = 4096;  // edges per binning/hist block
constexpr int NBKT_PAD = 1024;  // padded bucket count (actual = ceil(N/128) = 782)
constexpr int ACC_S    = 132;   // LDS accumulator row stride (bank stagger)

typedef __attribute__((ext_vector_type(8))) short bf16x8;
typedef __attribute__((ext_vector_type(4))) float f32x4;

__device__ __forceinline__ unsigned short rne_bf16(float f) {
    unsigned u = __float_as_uint(f);
    return (unsigned short)((u + 0x7FFF + ((u >> 16) & 1)) >> 16);
}

// ---------------------------------------------------------------------------
// One-time: W[k][f] f32 -> Wt_sw (transposed [f][k] bf16, XOR-pre-swizzled so
// a LINEAR LDS copy yields swizzled layout; element idx = f*128 + (k ^ ((f&7)<<3)))
// ---------------------------------------------------------------------------
__global__ __launch_bounds__(256) void transpose_W(
    const float* __restrict__ W, unsigned short* __restrict__ wt_sw)
{
    int idx = blockIdx.x * 256 + threadIdx.x;   // 16384 elems
    int k = idx >> 7, f = idx & 127;
    wt_sw[f * 128 + (k ^ ((f & 7) << 3))] = rne_bf16(W[idx]);
}

// ---------------------------------------------------------------------------
// Kernel 1: h = sigmoid(x @ W_gate + b) * (x @ W) via bf16x2 MFMA, h bf16.
// Tile 64 nodes x 128 feats, K=128. 4 waves; wave w covers feats [w*32,w*32+32).
// ---------------------------------------------------------------------------
__global__ __launch_bounds__(256) void mfma_gemm_gate(
    const float* __restrict__ x, const unsigned short* __restrict__ wt_sw,
    const float* __restrict__ Wg, const float* __restrict__ bg,
    __hip_bfloat16* __restrict__ h, int n_nodes)
{
    __shared__ __align__(16) char smem[65792];
    unsigned short* Ahi = (unsigned short*)smem;           // [64][128] swz, 16KB
    unsigned short* Alo = Ahi + 64 * 128;                  // 16KB
    unsigned short* Bt  = Alo + 64 * 128;                  // [128][128] swz, 32KB
    float*          Gs  = (float*)(Bt + 128 * 128);        // [64]
    unsigned short* Cbuf = (unsigned short*)smem;          // [64][136] reuse, 17KB

    const int t    = threadIdx.x;
    const int lane = t & 63;
    const int w    = t >> 6;
    const int node0 = blockIdx.x * BM;

    // ---- stage W tile: linear copy of pre-swizzled source (conflict-free)
    #pragma unroll
    for (int i = 0; i < 8; ++i) {
        int e0 = (i * 256 + t) * 8;
        *(int4*)&Bt[e0] = *(const int4*)&wt_sw[e0];
    }

    // ---- stage x tile as bf16 hi/lo, XOR-swizzled
    #pragma unroll
    for (int i = 0; i < 8; ++i) {
        int fidx = (i * 256 + t) * 4;          // flat f32 index in 64x128 tile
        int row  = fidx >> 7;
        int k    = fidx & 127;
        int node = node0 + row;
        float4 v = make_float4(0.f, 0.f, 0.f, 0.f);
        if (node < n_nodes) v = *(const float4*)(x + (size_t)node * D + k);
        unsigned short hi[4], lo[4];
        float vf[4] = {v.x, v.y, v.z, v.w};
        #pragma unroll
        for (int j = 0; j < 4; ++j) {
            hi[j] = rne_bf16(vf[j]);
            float fh = __uint_as_float((unsigned)hi[j] << 16);
            lo[j] = rne_bf16(vf[j] - fh);
        }
        int eidx = row * 128 + (k ^ ((row & 7) << 3));
        *(unsigned long long*)&Ahi[eidx] =
            (unsigned long long)hi[0] | ((unsigned long long)hi[1] << 16) |
            ((unsigned long long)hi[2] << 32) | ((unsigned long long)hi[3] << 48);
        *(unsigned long long*)&Alo[eidx] =
            (unsigned long long)lo[0] | ((unsigned long long)lo[1] << 16) |
            ((unsigned long long)lo[2] << 32) | ((unsigned long long)lo[3] << 48);
    }
    __syncthreads();

    // ---- gate (threads 0..63): gp = dot(x_hi[row], Wg); Gs = sigmoid(gp + b)
    if (t < BM) {
        float gp = 0.f;
        #pragma unroll
        for (int kq = 0; kq < 16; ++kq) {
            int eidx = t * 128 + ((kq * 8) ^ ((t & 7) << 3));
            unsigned long long a = *(const unsigned long long*)&Ahi[eidx];
            unsigned long long b = *(const unsigned long long*)&Ahi[eidx + 4];
            #pragma unroll
            for (int j = 0; j < 4; ++j) {
                gp += __uint_as_float((unsigned)((a >> (16 * j)) & 0xFFFF) << 16) * Wg[kq * 8 + j];
                gp += __uint_as_float((unsigned)((b >> (16 * j)) & 0xFFFF) << 16) * Wg[kq * 8 + 4 + j];
            }
        }
        Gs[t] = 1.f / (1.f + __expf(-(gp + bg[0])));
    }

    // ---- MFMA main loop
    f32x4 acc[4][2];
    #pragma unroll
    for (int m = 0; m < 4; ++m)
        #pragma unroll
        for (int n = 0; n < 2; ++n)
            acc[m][n] = (f32x4){0.f, 0.f, 0.f, 0.f};

    #pragma unroll
    for (int kk = 0; kk < 4; ++kk) {
        const int k0 = kk * 32 + (lane >> 4) * 8;
        bf16x8 bfr[2];
        #pragma unroll
        for (int n = 0; n < 2; ++n) {
            int f = w * 32 + n * 16 + (lane & 15);
            bfr[n] = *(const bf16x8*)&Bt[f * 128 + (k0 ^ ((f & 7) << 3))];
        }
        #pragma unroll
        for (int m = 0; m < 4; ++m) {
            int row = m * 16 + (lane & 15);
            int eidx = row * 128 + (k0 ^ ((row & 7) << 3));
            bf16x8 ah = *(const bf16x8*)&Ahi[eidx];
            bf16x8 al = *(const bf16x8*)&Alo[eidx];
            #pragma unroll
            for (int n = 0; n < 2; ++n) {
                acc[m][n] = __builtin_amdgcn_mfma_f32_16x16x32_bf16(ah, bfr[n], acc[m][n], 0, 0, 0);
                acc[m][n] = __builtin_amdgcn_mfma_f32_16x16x32_bf16(al, bfr[n], acc[m][n], 0, 0, 0);
            }
        }
    }
    __syncthreads();   // A/B LDS dead; Gs ready

    // ---- epilogue: gate-scale, cvt bf16, scatter to Cbuf [64][136]
    #pragma unroll
    for (int m = 0; m < 4; ++m) {
        #pragma unroll
        for (int n = 0; n < 2; ++n) {
            int feat = w * 32 + n * 16 + (lane & 15);
            #pragma unroll
            for (int j = 0; j < 4; ++j) {
                int rloc = m * 16 + (lane >> 4) * 4 + j;
                Cbuf[rloc * 136 + feat] = rne_bf16(acc[m][n][j] * Gs[rloc]);
            }
        }
    }
    __syncthreads();

    // ---- coalesced store: thread t -> row t>>2, feats (t&3)*32..+32
    {
        int row  = t >> 2;
        int fb   = (t & 3) * 32;
        int node = node0 + row;
        if (node < n_nodes) {
            __hip_bfloat16* hp = h + (size_t)node * D + fb;
            #pragma unroll
            for (int q = 0; q < 4; ++q)
                *(int4*)(hp + q * 8) = *(const int4*)&Cbuf[row * 136 + fb + q * 8];
        }
    }
}

// ---------------------------------------------------------------------------
// Bucket histogram (128-row buckets) via LDS, merged with global atomics.
// ---------------------------------------------------------------------------
__global__ __launch_bounds__(256) void hist_bkt(
    const int* __restrict__ er, int* __restrict__ cntb, int n_edges)
{
    __shared__ int lh[NBKT_PAD];
    const int t = threadIdx.x;
    for (int i = t; i < NBKT_PAD; i += 256) lh[i] = 0;
    __syncthreads();
    const int e0 = blockIdx.x * CHUNK;
    const int ecnt = min(CHUNK, n_edges - e0);
    for (int i = t; i < ecnt; i += 256) atomicAdd(&lh[er[e0 + i] >> 7], 1);
    __syncthreads();
    for (int i = t; i < NBKT_PAD; i += 256) {
        int v = lh[i];
        if (v) atomicAdd(&cntb[i], v);
    }
}

// ---------------------------------------------------------------------------
// Single-block exclusive scan of 1024 bucket counts; also zeroes gcursor.
// ---------------------------------------------------------------------------
__global__ __launch_bounds__(256) void scan_bkt(
    const int* __restrict__ cntb, int* __restrict__ bktStart,
    int* __restrict__ gcursor)
{
    __shared__ int wtot[4];
    const int t = threadIdx.x, lane = t & 63, w = t >> 6;
    const int base = t * 4;
    int v[4], tsum = 0;
    #pragma unroll
    for (int j = 0; j < 4; ++j) { v[j] = cntb[base + j]; tsum += v[j]; }
    int x = tsum;
    #pragma unroll
    for (int d = 1; d < 64; d <<= 1) {
        int y = __shfl_up(x, d);
        if (lane >= d) x += y;
    }
    if (lane == 63) wtot[w] = x;
    __syncthreads();
    int woff = 0;
    for (int i = 0; i < w; ++i) woff += wtot[i];
    int run = woff + x - tsum;
    #pragma unroll
    for (int j = 0; j < 4; ++j) { bktStart[base + j] = run; run += v[j]; }
    if (t == 255) bktStart[NBKT_PAD] = run;
    #pragma unroll
    for (int j = 0; j < 4; ++j) gcursor[base + j] = 0;
}

// ---------------------------------------------------------------------------
// Bin edges into 128-row buckets via LDS staging (coalesced bucket runs).
// Entry: {packed = col | (row&127)<<17, val_bits}. col < 2^17 (N=100k).
// ---------------------------------------------------------------------------
__global__ __launch_bounds__(256) void bin_pass(
    const int* __restrict__ er, const int* __restrict__ ec,
    const float* __restrict__ ev, const int* __restrict__ bktStart,
    int* __restrict__ gcursor, uint2* __restrict__ bucketArr, int n_edges)
{
    __shared__ uint2 staged[CHUNK];            // 32 KB
    __shared__ unsigned short bkt_of[CHUNK];   // 8 KB
    __shared__ int lcnt[NBKT_PAD];             // 4 KB each
    __shared__ int lbase[NBKT_PAD];
    __shared__ int gbase[NBKT_PAD];
    __shared__ int wt[4];

    const int t = threadIdx.x;
    const int lane = t & 63, w = t >> 6;
    const int e0 = blockIdx.x * CHUNK;
    const int ecnt = min(CHUNK, n_edges - e0);

    for (int i = t; i < NBKT_PAD; i += 256) lcnt[i] = 0;
    __syncthreads();

    for (int i = t; i < ecnt; i += 256) atomicAdd(&lcnt[er[e0 + i] >> 7], 1);
    __syncthreads();

    {   // exclusive scan of 1024 counters (4 per thread); reset lcnt as cursor
        const int base = t * 4;
        int v[4], tsum = 0;
        #pragma unroll
        for (int j = 0; j < 4; ++j) { v[j] = lcnt[base + j]; tsum += v[j]; }
        int x = tsum;
        #pragma unroll
        for (int d = 1; d < 64; d <<= 1) {
            int y = __shfl_up(x, d);
            if (lane >= d) x += y;
        }
        if (lane == 63) wt[w] = x;
        __syncthreads();
        int woff = 0;
        for (int i = 0; i < w; ++i) woff += wt[i];
        int run = woff + x - tsum;
        #pragma unroll
        for (int j = 0; j < 4; ++j) { lbase[base + j] = run; run += v[j]; lcnt[base + j] = 0; }
    }
    __syncthreads();

    // scatter into LDS, bucket-grouped
    for (int i = t; i < ecnt; i += 256) {
        int r = er[e0 + i];
        int b = r >> 7;
        int p = lbase[b] + atomicAdd(&lcnt[b], 1);
        staged[p] = make_uint2((unsigned)ec[e0 + i] | ((unsigned)(r & 127) << 17),
                               (unsigned)__float_as_int(ev[e0 + i]));
        bkt_of[p] = (unsigned short)b;
    }
    __syncthreads();

    // reserve global space per bucket
    for (int i = t; i < NBKT_PAD; i += 256) {
        int c = lcnt[i];
        if (c) gbase[i] = bktStart[i] + atomicAdd(&gcursor[i], c);
    }
    __syncthreads();

    // bulk copy: contiguous LDS runs -> per-bucket global regions
    for (int i = t; i < ecnt; i += 256) {
        int b = bkt_of[i];
        bucketArr[gbase[b] + (i - lbase[b])] = staged[i];
    }
}

// ---------------------------------------------------------------------------
// Bucket-accumulate: one block per 128-row bucket; f32 LDS accumulator.
// 8 edges in flight per wave (4 groups x 2 slots); ds_add_f32 with stagger.
// ---------------------------------------------------------------------------
__global__ __launch_bounds__(256) void bucket_acc(
    const int* __restrict__ bktStart, const uint2* __restrict__ bucketArr,
    const __hip_bfloat16* __restrict__ h, float* __restrict__ out, int n_nodes)
{
    __shared__ float acc[128 * ACC_S];   // 67.6 KB
    const int t = threadIdx.x, lane = t & 63, w = t >> 6;
    const int row0 = blockIdx.x << 7;
    const int s = bktStart[blockIdx.x];
    const int e = bktStart[blockIdx.x + 1];

    {   // zero accumulator (float4)
        float4 z = make_float4(0.f, 0.f, 0.f, 0.f);
        float4* a4 = (float4*)acc;
        for (int i = t; i < 128 * ACC_S / 4; i += 256) a4[i] = z;
    }
    __syncthreads();

    const int g = lane >> 4;          // edge group 0..3
    const int p = lane & 15;          // feat block (8 feats)

    for (int base = s + w * 8; base < e; base += 32) {
        const int i0 = base + g;
        const int i1 = base + g + 4;
        uint2 e0 = (i0 < e) ? bucketArr[i0] : make_uint2(0u, 0u);
        uint2 e1 = (i1 < e) ? bucketArr[i1] : make_uint2(0u, 0u);
        float v0 = __uint_as_float(e0.y);
        float v1 = __uint_as_float(e1.y);
        int c0 = (int)(e0.x & 0x1FFFFu), r0 = (int)((e0.x >> 17) & 127u);
        int c1 = (int)(e1.x & 0x1FFFFu), r1 = (int)((e1.x >> 17) & 127u);
        const int4 h0 = *(const int4*)(h + (size_t)c0 * D + p * 8);
        const int4 h1 = *(const int4*)(h + (size_t)c1 * D + p * 8);

        float f0[8], f1[8];
        {
            unsigned d0 = (unsigned)h0.x, d1 = (unsigned)h0.y, d2 = (unsigned)h0.z, d3 = (unsigned)h0.w;
            f0[0] = __uint_as_float(d0 << 16); f0[1] = __uint_as_float(d0 & 0xFFFF0000u);
            f0[2] = __uint_as_float(d1 << 16); f0[3] = __uint_as_float(d1 & 0xFFFF0000u);
            f0[4] = __uint_as_float(d2 << 16); f0[5] = __uint_as_float(d2 & 0xFFFF0000u);
            f0[6] = __uint_as_float(d3 << 16); f0[7] = __uint_as_float(d3 & 0xFFFF0000u);
            unsigned g0 = (unsigned)h1.x, g1 = (unsigned)h1.y, g2 = (unsigned)h1.z, g3 = (unsigned)h1.w;
            f1[0] = __uint_as_float(g0 << 16); f1[1] = __uint_as_float(g0 & 0xFFFF0000u);
            f1[2] = __uint_as_float(g1 << 16); f1[3] = __uint_as_float(g1 & 0xFFFF0000u);
            f1[4] = __uint_as_float(g2 << 16); f1[5] = __uint_as_float(g2 & 0xFFFF0000u);
            f1[6] = __uint_as_float(g3 << 16); f1[7] = __uint_as_float(g3 & 0xFFFF0000u);
        }
        float* a0 = &acc[r0 * ACC_S + p * 8];
        float* a1 = &acc[r1 * ACC_S + p * 8];
        #pragma unroll
        for (int j = 0; j < 8; ++j) {
            int jj = (j + p) & 7;           // per-lane round stagger
            atomicAdd(&a0[jj], v0 * f0[jj]);
        }
        #pragma unroll
        for (int j = 0; j < 8; ++j) {
            int jj = (j + p + 4) & 7;
            atomicAdd(&a1[jj], v1 * f1[jj]);
        }
    }
    __syncthreads();

    // write 128 rows coalesced (32 threads per row)
    for (int i = t; i < 128 * 32; i += 256) {
        int r = i >> 5, q = i & 31;
        int node = row0 + r;
        if (node < n_nodes)
            *(float4*)(out + (size_t)node * D + q * 4) = *(const float4*)&acc[r * ACC_S + q * 4];
    }
}

// ---------------------------------------------------------------------------
// Fallback (ws too small): atomic scatter
// ---------------------------------------------------------------------------
__global__ __launch_bounds__(256) void scatter_edges(
    const int* __restrict__ er, const int* __restrict__ ec,
    const float* __restrict__ ev, const __hip_bfloat16* __restrict__ h,
    float* __restrict__ out, int n_edges)
{
    int gw   = (blockIdx.x * 256 + threadIdx.x) >> 6;
    int lane = threadIdx.x & 63;
    if (gw >= n_edges) return;
    int r = er[gw];
    int c = ec[gw];
    float v = ev[gw];
    unsigned hv = *(const unsigned*)(h + (size_t)c * D + lane * 2);
    float* op = out + (size_t)r * D + lane * 2;
    atomicAdd(op,     v * __uint_as_float(hv << 16));
    atomicAdd(op + 1, v * __uint_as_float(hv & 0xFFFF0000u));
}

extern "C" void kernel_launch(void* const* d_in, const int* in_sizes, int n_in,
                              void* d_out, int out_size, void* d_ws, size_t ws_size,
                              hipStream_t stream) {
    const float* x  = (const float*)d_in[0];
    const int*   er = (const int*)d_in[1];
    const int*   ec = (const int*)d_in[2];
    const float* ev = (const float*)d_in[3];
    const float* W  = (const float*)d_in[4];
    const float* Wg = (const float*)d_in[5];
    const float* bg = (const float*)d_in[6];
    float* out = (float*)d_out;

    const int n_nodes = in_sizes[0] / D;
    const int n_edges = in_sizes[1];
    const int nbkt = (n_nodes + 127) >> 7;   // 128-row buckets

    char* ws = (char*)d_ws;
    size_t off = 0;
    auto alloc = [&](size_t bytes) {
        char* p = ws + off;
        off += (bytes + 15) & ~size_t(15);
        return p;
    };
    __hip_bfloat16* h = (__hip_bfloat16*)alloc((size_t)n_nodes * D * sizeof(__hip_bfloat16));
    unsigned short* wt_sw = (unsigned short*)alloc((size_t)D * D * sizeof(unsigned short));
    uint2* bucketArr = (uint2*)alloc((size_t)n_edges * sizeof(uint2));
    int*   bktStart  = (int*)  alloc((NBKT_PAD + 1) * sizeof(int));
    int*   cntb      = (int*)  alloc(NBKT_PAD * sizeof(int));
    int*   gcursor   = (int*)  alloc(NBKT_PAD * sizeof(int));
    bool have_ws = off <= ws_size;

    // W -> transposed, pre-swizzled bf16
    transpose_W<<<D * D / 256, 256, 0, stream>>>(W, wt_sw);

    // h = gate(x) * (x @ W) via MFMA
    dim3 gemm_grid((n_nodes + BM - 1) / BM);
    mfma_gemm_gate<<<gemm_grid, 256, 0, stream>>>(x, wt_sw, Wg, bg, h, n_nodes);

    if (have_ws) {
        hipMemsetAsync(cntb, 0, NBKT_PAD * sizeof(int), stream);
        int cb = (n_edges + CHUNK - 1) / CHUNK;
        hist_bkt<<<cb, 256, 0, stream>>>(er, cntb, n_edges);
        scan_bkt<<<1, 256, 0, stream>>>(cntb, bktStart, gcursor);
        bin_pass<<<cb, 256, 0, stream>>>(er, ec, ev, bktStart, gcursor, bucketArr, n_edges);
        bucket_acc<<<nbkt, 256, 0, stream>>>(bktStart, bucketArr, h, out, n_nodes);
    } else {
        hipMemsetAsync(d_out, 0, (size_t)out_size * sizeof(float), stream);
        int blocks = (n_edges + 3) / 4;
        scatter_edges<<<blocks, 256, 0, stream>>>(er, ec, ev, h, out, n_edges);
    }
}

// Round 8
// 168.410 us; speedup vs baseline: 8.4297x; 8.4297x over previous
//
#include <hip/hip_runtime.h>
#include <hip/hip_bf16.h>

constexpr int D        = 128;   // feature dim = K = UNITS
constexpr int BM       = 64;    // nodes per block in GEMM
constexpr int CHUNK    = 4096;  // edges per binning/hist block
constexpr int NBKT_PAD = 1024;  // padded bucket count (actual = ceil(N/128) = 782)
constexpr int BKT_CAP  = 3072;  // fine-sort LDS capacity (mean 2048, sigma ~45)

typedef __attribute__((ext_vector_type(8))) short bf16x8;
typedef __attribute__((ext_vector_type(4))) float f32x4;

__device__ __forceinline__ unsigned short rne_bf16(float f) {
    unsigned u = __float_as_uint(f);
    return (unsigned short)((u + 0x7FFF + ((u >> 16) & 1)) >> 16);
}

// ---------------------------------------------------------------------------
// One-time: W[k][f] f32 -> Wt_sw (transposed [f][k] bf16, XOR-pre-swizzled)
// ---------------------------------------------------------------------------
__global__ __launch_bounds__(256) void transpose_W(
    const float* __restrict__ W, unsigned short* __restrict__ wt_sw)
{
    int idx = blockIdx.x * 256 + threadIdx.x;   // 16384 elems
    int k = idx >> 7, f = idx & 127;
    wt_sw[f * 128 + (k ^ ((f & 7) << 3))] = rne_bf16(W[idx]);
}

// ---------------------------------------------------------------------------
// Kernel 1: h = sigmoid(x @ W_gate + b) * (x @ W) via bf16x2 MFMA, h bf16.
// ---------------------------------------------------------------------------
__global__ __launch_bounds__(256) void mfma_gemm_gate(
    const float* __restrict__ x, const unsigned short* __restrict__ wt_sw,
    const float* __restrict__ Wg, const float* __restrict__ bg,
    __hip_bfloat16* __restrict__ h, int n_nodes)
{
    __shared__ __align__(16) char smem[65792];
    unsigned short* Ahi = (unsigned short*)smem;           // [64][128] swz, 16KB
    unsigned short* Alo = Ahi + 64 * 128;                  // 16KB
    unsigned short* Bt  = Alo + 64 * 128;                  // [128][128] swz, 32KB
    float*          Gs  = (float*)(Bt + 128 * 128);        // [64]
    unsigned short* Cbuf = (unsigned short*)smem;          // [64][136] reuse, 17KB

    const int t    = threadIdx.x;
    const int lane = t & 63;
    const int w    = t >> 6;
    const int node0 = blockIdx.x * BM;

    // ---- stage W tile: linear copy of pre-swizzled source (conflict-free)
    #pragma unroll
    for (int i = 0; i < 8; ++i) {
        int e0 = (i * 256 + t) * 8;
        *(int4*)&Bt[e0] = *(const int4*)&wt_sw[e0];
    }

    // ---- stage x tile as bf16 hi/lo, XOR-swizzled
    #pragma unroll
    for (int i = 0; i < 8; ++i) {
        int fidx = (i * 256 + t) * 4;          // flat f32 index in 64x128 tile
        int row  = fidx >> 7;
        int k    = fidx & 127;
        int node = node0 + row;
        float4 v = make_float4(0.f, 0.f, 0.f, 0.f);
        if (node < n_nodes) v = *(const float4*)(x + (size_t)node * D + k);
        unsigned short hi[4], lo[4];
        float vf[4] = {v.x, v.y, v.z, v.w};
        #pragma unroll
        for (int j = 0; j < 4; ++j) {
            hi[j] = rne_bf16(vf[j]);
            float fh = __uint_as_float((unsigned)hi[j] << 16);
            lo[j] = rne_bf16(vf[j] - fh);
        }
        int eidx = row * 128 + (k ^ ((row & 7) << 3));
        *(unsigned long long*)&Ahi[eidx] =
            (unsigned long long)hi[0] | ((unsigned long long)hi[1] << 16) |
            ((unsigned long long)hi[2] << 32) | ((unsigned long long)hi[3] << 48);
        *(unsigned long long*)&Alo[eidx] =
            (unsigned long long)lo[0] | ((unsigned long long)lo[1] << 16) |
            ((unsigned long long)lo[2] << 32) | ((unsigned long long)lo[3] << 48);
    }
    __syncthreads();

    // ---- gate (threads 0..63)
    if (t < BM) {
        float gp = 0.f;
        #pragma unroll
        for (int kq = 0; kq < 16; ++kq) {
            int eidx = t * 128 + ((kq * 8) ^ ((t & 7) << 3));
            unsigned long long a = *(const unsigned long long*)&Ahi[eidx];
            unsigned long long b = *(const unsigned long long*)&Ahi[eidx + 4];
            #pragma unroll
            for (int j = 0; j < 4; ++j) {
                gp += __uint_as_float((unsigned)((a >> (16 * j)) & 0xFFFF) << 16) * Wg[kq * 8 + j];
                gp += __uint_as_float((unsigned)((b >> (16 * j)) & 0xFFFF) << 16) * Wg[kq * 8 + 4 + j];
            }
        }
        Gs[t] = 1.f / (1.f + __expf(-(gp + bg[0])));
    }

    // ---- MFMA main loop
    f32x4 acc[4][2];
    #pragma unroll
    for (int m = 0; m < 4; ++m)
        #pragma unroll
        for (int n = 0; n < 2; ++n)
            acc[m][n] = (f32x4){0.f, 0.f, 0.f, 0.f};

    #pragma unroll
    for (int kk = 0; kk < 4; ++kk) {
        const int k0 = kk * 32 + (lane >> 4) * 8;
        bf16x8 bfr[2];
        #pragma unroll
        for (int n = 0; n < 2; ++n) {
            int f = w * 32 + n * 16 + (lane & 15);
            bfr[n] = *(const bf16x8*)&Bt[f * 128 + (k0 ^ ((f & 7) << 3))];
        }
        #pragma unroll
        for (int m = 0; m < 4; ++m) {
            int row = m * 16 + (lane & 15);
            int eidx = row * 128 + (k0 ^ ((row & 7) << 3));
            bf16x8 ah = *(const bf16x8*)&Ahi[eidx];
            bf16x8 al = *(const bf16x8*)&Alo[eidx];
            #pragma unroll
            for (int n = 0; n < 2; ++n) {
                acc[m][n] = __builtin_amdgcn_mfma_f32_16x16x32_bf16(ah, bfr[n], acc[m][n], 0, 0, 0);
                acc[m][n] = __builtin_amdgcn_mfma_f32_16x16x32_bf16(al, bfr[n], acc[m][n], 0, 0, 0);
            }
        }
    }
    __syncthreads();   // A/B LDS dead; Gs ready

    // ---- epilogue: gate-scale, cvt bf16, scatter to Cbuf [64][136]
    #pragma unroll
    for (int m = 0; m < 4; ++m) {
        #pragma unroll
        for (int n = 0; n < 2; ++n) {
            int feat = w * 32 + n * 16 + (lane & 15);
            #pragma unroll
            for (int j = 0; j < 4; ++j) {
                int rloc = m * 16 + (lane >> 4) * 4 + j;
                Cbuf[rloc * 136 + feat] = rne_bf16(acc[m][n][j] * Gs[rloc]);
            }
        }
    }
    __syncthreads();

    // ---- coalesced store
    {
        int row  = t >> 2;
        int fb   = (t & 3) * 32;
        int node = node0 + row;
        if (node < n_nodes) {
            __hip_bfloat16* hp = h + (size_t)node * D + fb;
            #pragma unroll
            for (int q = 0; q < 4; ++q)
                *(int4*)(hp + q * 8) = *(const int4*)&Cbuf[row * 136 + fb + q * 8];
        }
    }
}

// ---------------------------------------------------------------------------
// Bucket histogram (128-row buckets) via LDS, merged with global atomics.
// ---------------------------------------------------------------------------
__global__ __launch_bounds__(256) void hist_bkt(
    const int* __restrict__ er, int* __restrict__ cntb, int n_edges)
{
    __shared__ int lh[NBKT_PAD];
    const int t = threadIdx.x;
    for (int i = t; i < NBKT_PAD; i += 256) lh[i] = 0;
    __syncthreads();
    const int e0 = blockIdx.x * CHUNK;
    const int ecnt = min(CHUNK, n_edges - e0);
    for (int i = t; i < ecnt; i += 256) atomicAdd(&lh[er[e0 + i] >> 7], 1);
    __syncthreads();
    for (int i = t; i < NBKT_PAD; i += 256) {
        int v = lh[i];
        if (v) atomicAdd(&cntb[i], v);
    }
}

// ---------------------------------------------------------------------------
// Single-block exclusive scan of 1024 bucket counts; zeroes gcursor;
// writes rowStart[n_nodes] = n_edges sentinel.
// ---------------------------------------------------------------------------
__global__ __launch_bounds__(256) void scan_bkt(
    const int* __restrict__ cntb, int* __restrict__ bktStart,
    int* __restrict__ gcursor, int* __restrict__ rowStart,
    int n_nodes, int n_edges)
{
    __shared__ int wtot[4];
    const int t = threadIdx.x, lane = t & 63, w = t >> 6;
    const int base = t * 4;
    int v[4], tsum = 0;
    #pragma unroll
    for (int j = 0; j < 4; ++j) { v[j] = cntb[base + j]; tsum += v[j]; }
    int x = tsum;
    #pragma unroll
    for (int d = 1; d < 64; d <<= 1) {
        int y = __shfl_up(x, d);
        if (lane >= d) x += y;
    }
    if (lane == 63) wtot[w] = x;
    __syncthreads();
    int woff = 0;
    for (int i = 0; i < w; ++i) woff += wtot[i];
    int run = woff + x - tsum;
    #pragma unroll
    for (int j = 0; j < 4; ++j) { bktStart[base + j] = run; run += v[j]; }
    if (t == 255) { bktStart[NBKT_PAD] = run; rowStart[n_nodes] = n_edges; }
    #pragma unroll
    for (int j = 0; j < 4; ++j) gcursor[base + j] = 0;
}

// ---------------------------------------------------------------------------
// Bin edges into 128-row buckets via LDS staging (coalesced bucket runs).
// Entry: {packed = col | (row&127)<<17, val_bits}. col < 2^17 (N=100k).
// ---------------------------------------------------------------------------
__global__ __launch_bounds__(256) void bin_pass(
    const int* __restrict__ er, const int* __restrict__ ec,
    const float* __restrict__ ev, const int* __restrict__ bktStart,
    int* __restrict__ gcursor, uint2* __restrict__ bucketArr, int n_edges)
{
    __shared__ uint2 staged[CHUNK];            // 32 KB
    __shared__ unsigned short bkt_of[CHUNK];   // 8 KB
    __shared__ int lcnt[NBKT_PAD];             // 4 KB each
    __shared__ int lbase[NBKT_PAD];
    __shared__ int gbase[NBKT_PAD];
    __shared__ int wt[4];

    const int t = threadIdx.x;
    const int lane = t & 63, w = t >> 6;
    const int e0 = blockIdx.x * CHUNK;
    const int ecnt = min(CHUNK, n_edges - e0);

    for (int i = t; i < NBKT_PAD; i += 256) lcnt[i] = 0;
    __syncthreads();

    for (int i = t; i < ecnt; i += 256) atomicAdd(&lcnt[er[e0 + i] >> 7], 1);
    __syncthreads();

    {   // exclusive scan of 1024 counters (4 per thread); reset lcnt as cursor
        const int base = t * 4;
        int v[4], tsum = 0;
        #pragma unroll
        for (int j = 0; j < 4; ++j) { v[j] = lcnt[base + j]; tsum += v[j]; }
        int x = tsum;
        #pragma unroll
        for (int d = 1; d < 64; d <<= 1) {
            int y = __shfl_up(x, d);
            if (lane >= d) x += y;
        }
        if (lane == 63) wt[w] = x;
        __syncthreads();
        int woff = 0;
        for (int i = 0; i < w; ++i) woff += wt[i];
        int run = woff + x - tsum;
        #pragma unroll
        for (int j = 0; j < 4; ++j) { lbase[base + j] = run; run += v[j]; lcnt[base + j] = 0; }
    }
    __syncthreads();

    // scatter into LDS, bucket-grouped
    for (int i = t; i < ecnt; i += 256) {
        int r = er[e0 + i];
        int b = r >> 7;
        int p = lbase[b] + atomicAdd(&lcnt[b], 1);
        staged[p] = make_uint2((unsigned)ec[e0 + i] | ((unsigned)(r & 127) << 17),
                               (unsigned)__float_as_int(ev[e0 + i]));
        bkt_of[p] = (unsigned short)b;
    }
    __syncthreads();

    // reserve global space per bucket
    for (int i = t; i < NBKT_PAD; i += 256) {
        int c = lcnt[i];
        if (c) gbase[i] = bktStart[i] + atomicAdd(&gcursor[i], c);
    }
    __syncthreads();

    // bulk copy: contiguous LDS runs -> per-bucket global regions
    for (int i = t; i < ecnt; i += 256) {
        int b = bkt_of[i];
        bucketArr[gbase[b] + (i - lbase[b])] = staged[i];
    }
}

// ---------------------------------------------------------------------------
// Fine counting-sort of each 128-row bucket in LDS; ALSO emits per-row CSR
// rowStart[] (replaces the old per-row histogram + 3-pass scan).
// ---------------------------------------------------------------------------
__global__ __launch_bounds__(256) void fine_sort(
    const int* __restrict__ bktStart, uint2* __restrict__ bucketArr,
    int* __restrict__ rowStart, int* __restrict__ ovf, int n_nodes)
{
    __shared__ uint2 inStg[BKT_CAP];   // 24 KB
    __shared__ int rcnt[128];
    __shared__ int rbase[128];
    __shared__ int wt2[2];

    const int t = threadIdx.x;
    const int lane = t & 63, w = t >> 6;
    const int b = blockIdx.x;
    const int r0 = b << 7;
    const int s = bktStart[b];
    const int e = bktStart[b + 1];
    const int cnt = e - s;

    if (cnt > BKT_CAP || cnt == 0) {           // overflow (stat. impossible) or empty
        if (cnt > BKT_CAP && t == 0) ovf[b] = 1;
        if (t < 128 && r0 + t < n_nodes) rowStart[r0 + t] = s;
        return;
    }

    for (int i = t; i < cnt; i += 256) inStg[i] = bucketArr[s + i];
    if (t < 128) rcnt[t] = 0;
    __syncthreads();

    for (int i = t; i < cnt; i += 256)
        atomicAdd(&rcnt[(inStg[i].x >> 17) & 127], 1);
    __syncthreads();

    // exclusive scan of 128 row counts (waves 0,1)
    int v = 0, x = 0;
    if (t < 128) {
        v = rcnt[t];
        x = v;
        #pragma unroll
        for (int d = 1; d < 64; d <<= 1) {
            int y = __shfl_up(x, d);
            if (lane >= d) x += y;
        }
        if (lane == 63) wt2[w] = x;
    }
    __syncthreads();
    if (t < 128) {
        int rb = (w ? wt2[0] : 0) + x - v;
        rbase[t] = rb;
        if (r0 + t < n_nodes) rowStart[r0 + t] = s + rb;   // per-row CSR
        rcnt[t] = 0;
    }
    __syncthreads();

    // scatter sorted entries to global (L2-hot 16-24KB window)
    for (int i = t; i < cnt; i += 256) {
        uint2 pe = inStg[i];
        int rl = (pe.x >> 17) & 127;
        int p  = rbase[rl] + atomicAdd(&rcnt[rl], 1);
        bucketArr[s + p] = pe;
    }
}

// ---------------------------------------------------------------------------
// Gather-reduce: one wave per row, 8 edges in flight (4 groups x 2 slots).
// ---------------------------------------------------------------------------
__global__ __launch_bounds__(256) void gather_rows(
    const int* __restrict__ rowStart, const uint2* __restrict__ sorted,
    const int* __restrict__ ovf, const __hip_bfloat16* __restrict__ h,
    float* __restrict__ out, int n_nodes)
{
    int row  = (blockIdx.x * 256 + threadIdx.x) >> 6;
    int lane = threadIdx.x & 63;
    if (row >= n_nodes) return;

    int b = row >> 7;
    bool filter = ovf[b] != 0;
    int s, e;
    if (!filter) { s = rowStart[row]; e = rowStart[row + 1]; }
    else { s = rowStart[b << 7]; e = rowStart[min((b + 1) << 7, n_nodes)]; }

    const int g = lane >> 4;          // edge slot within quad 0..3
    const int p = lane & 15;          // feat block (8 feats)
    const unsigned target = (unsigned)(row & 127);

    float acc[8];
    #pragma unroll
    for (int j = 0; j < 8; ++j) acc[j] = 0.f;

    for (int base = s; base < e; base += 8) {
        int i0 = base + g;
        int i1 = base + g + 4;
        float v0 = 0.f, v1 = 0.f;
        int c0 = 0, c1 = 0;
        if (i0 < e) {
            uint2 pk = sorted[i0];
            if (!filter || ((pk.x >> 17) & 127) == target) {
                v0 = __uint_as_float(pk.y);
                c0 = (int)(pk.x & 0x1FFFFu);
            }
        }
        if (i1 < e) {
            uint2 pk = sorted[i1];
            if (!filter || ((pk.x >> 17) & 127) == target) {
                v1 = __uint_as_float(pk.y);
                c1 = (int)(pk.x & 0x1FFFFu);
            }
        }
        const int4 h0 = *(const int4*)(h + (size_t)c0 * D + p * 8);
        const int4 h1 = *(const int4*)(h + (size_t)c1 * D + p * 8);
        {
            unsigned d0 = (unsigned)h0.x, d1 = (unsigned)h0.y, d2 = (unsigned)h0.z, d3 = (unsigned)h0.w;
            acc[0] += v0 * __uint_as_float(d0 << 16);
            acc[1] += v0 * __uint_as_float(d0 & 0xFFFF0000u);
            acc[2] += v0 * __uint_as_float(d1 << 16);
            acc[3] += v0 * __uint_as_float(d1 & 0xFFFF0000u);
            acc[4] += v0 * __uint_as_float(d2 << 16);
            acc[5] += v0 * __uint_as_float(d2 & 0xFFFF0000u);
            acc[6] += v0 * __uint_as_float(d3 << 16);
            acc[7] += v0 * __uint_as_float(d3 & 0xFFFF0000u);
        }
        {
            unsigned d0 = (unsigned)h1.x, d1 = (unsigned)h1.y, d2 = (unsigned)h1.z, d3 = (unsigned)h1.w;
            acc[0] += v1 * __uint_as_float(d0 << 16);
            acc[1] += v1 * __uint_as_float(d0 & 0xFFFF0000u);
            acc[2] += v1 * __uint_as_float(d1 << 16);
            acc[3] += v1 * __uint_as_float(d1 & 0xFFFF0000u);
            acc[4] += v1 * __uint_as_float(d2 << 16);
            acc[5] += v1 * __uint_as_float(d2 & 0xFFFF0000u);
            acc[6] += v1 * __uint_as_float(d3 << 16);
            acc[7] += v1 * __uint_as_float(d3 & 0xFFFF0000u);
        }
    }

    // reduce across the 4 edge groups (lane bits 4,5)
    #pragma unroll
    for (int j = 0; j < 8; ++j) {
        acc[j] += __shfl_xor(acc[j], 16);
        acc[j] += __shfl_xor(acc[j], 32);
    }

    if (lane < 16) {
        float* op = out + (size_t)row * D + lane * 8;
        *(float4*)(op)     = make_float4(acc[0], acc[1], acc[2], acc[3]);
        *(float4*)(op + 4) = make_float4(acc[4], acc[5], acc[6], acc[7]);
    }
}

// ---------------------------------------------------------------------------
// Fallback (ws too small): atomic scatter
// ---------------------------------------------------------------------------
__global__ __launch_bounds__(256) void scatter_edges(
    const int* __restrict__ er, const int* __restrict__ ec,
    const float* __restrict__ ev, const __hip_bfloat16* __restrict__ h,
    float* __restrict__ out, int n_edges)
{
    int gw   = (blockIdx.x * 256 + threadIdx.x) >> 6;
    int lane = threadIdx.x & 63;
    if (gw >= n_edges) return;
    int r = er[gw];
    int c = ec[gw];
    float v = ev[gw];
    unsigned hv = *(const unsigned*)(h + (size_t)c * D + lane * 2);
    float* op = out + (size_t)r * D + lane * 2;
    atomicAdd(op,     v * __uint_as_float(hv << 16));
    atomicAdd(op + 1, v * __uint_as_float(hv & 0xFFFF0000u));
}

extern "C" void kernel_launch(void* const* d_in, const int* in_sizes, int n_in,
                              void* d_out, int out_size, void* d_ws, size_t ws_size,
                              hipStream_t stream) {
    const float* x  = (const float*)d_in[0];
    const int*   er = (const int*)d_in[1];
    const int*   ec = (const int*)d_in[2];
    const float* ev = (const float*)d_in[3];
    const float* W  = (const float*)d_in[4];
    const float* Wg = (const float*)d_in[5];
    const float* bg = (const float*)d_in[6];
    float* out = (float*)d_out;

    const int n_nodes = in_sizes[0] / D;
    const int n_edges = in_sizes[1];
    const int nbkt = (n_nodes + 127) >> 7;   // 128-row buckets

    char* ws = (char*)d_ws;
    size_t off = 0;
    auto alloc = [&](size_t bytes) {
        char* p = ws + off;
        off += (bytes + 15) & ~size_t(15);
        return p;
    };
    __hip_bfloat16* h = (__hip_bfloat16*)alloc((size_t)n_nodes * D * sizeof(__hip_bfloat16));
    unsigned short* wt_sw = (unsigned short*)alloc((size_t)D * D * sizeof(unsigned short));
    uint2* bucketArr = (uint2*)alloc((size_t)n_edges * sizeof(uint2));
    int*   rowStart  = (int*)  alloc((size_t)(n_nodes + 1) * sizeof(int));
    int*   bktStart  = (int*)  alloc((NBKT_PAD + 1) * sizeof(int));
    int*   cntb      = (int*)  alloc(NBKT_PAD * sizeof(int));   // | contiguous
    int*   gcursor   = (int*)  alloc(NBKT_PAD * sizeof(int));   // | memset
    int*   ovf       = (int*)  alloc(NBKT_PAD * sizeof(int));   // | below
    bool have_ws = off <= ws_size;

    // W -> transposed, pre-swizzled bf16
    transpose_W<<<D * D / 256, 256, 0, stream>>>(W, wt_sw);

    // h = gate(x) * (x @ W) via MFMA
    dim3 gemm_grid((n_nodes + BM - 1) / BM);
    mfma_gemm_gate<<<gemm_grid, 256, 0, stream>>>(x, wt_sw, Wg, bg, h, n_nodes);

    if (have_ws) {
        hipMemsetAsync(cntb, 0, 3 * NBKT_PAD * sizeof(int), stream);  // cntb+gcursor+ovf
        int cb = (n_edges + CHUNK - 1) / CHUNK;
        hist_bkt<<<cb, 256, 0, stream>>>(er, cntb, n_edges);
        scan_bkt<<<1, 256, 0, stream>>>(cntb, bktStart, gcursor, rowStart, n_nodes, n_edges);
        bin_pass<<<cb, 256, 0, stream>>>(er, ec, ev, bktStart, gcursor, bucketArr, n_edges);
        fine_sort<<<nbkt, 256, 0, stream>>>(bktStart, bucketArr, rowStart, ovf, n_nodes);
        int rb = (n_nodes * 64 + 255) / 256;
        gather_rows<<<rb, 256, 0, stream>>>(rowStart, bucketArr, ovf, h, out, n_nodes);
    } else {
        hipMemsetAsync(d_out, 0, (size_t)out_size * sizeof(float), stream);
        int blocks = (n_edges + 3) / 4;
        scatter_edges<<<blocks, 256, 0, stream>>>(er, ec, ev, h, out, n_edges);
    }
}

// Round 9
// 157.262 us; speedup vs baseline: 9.0272x; 1.0709x over previous
//
#include <hip/hip_runtime.h>
#include <hip/hip_bf16.h>

constexpr int D        = 128;   // feature dim = K = UNITS
constexpr int BM       = 64;    // nodes per block in GEMM
constexpr int CHUNK    = 4096;  // edges per binning/hist block
constexpr int NBKT_PAD = 1024;  // padded bucket count (actual = ceil(N/128) = 782)
constexpr int BKT_CAP  = 3072;  // sort LDS capacity (mean 2048, sigma ~45 -> 22 sigma)

typedef __attribute__((ext_vector_type(8))) short bf16x8;
typedef __attribute__((ext_vector_type(4))) float f32x4;

__device__ __forceinline__ unsigned short rne_bf16(float f) {
    unsigned u = __float_as_uint(f);
    return (unsigned short)((u + 0x7FFF + ((u >> 16) & 1)) >> 16);
}

// ---------------------------------------------------------------------------
// One-time: W[k][f] f32 -> Wt_sw (transposed [f][k] bf16, XOR-pre-swizzled)
// ---------------------------------------------------------------------------
__global__ __launch_bounds__(256) void transpose_W(
    const float* __restrict__ W, unsigned short* __restrict__ wt_sw)
{
    int idx = blockIdx.x * 256 + threadIdx.x;   // 16384 elems
    int k = idx >> 7, f = idx & 127;
    wt_sw[f * 128 + (k ^ ((f & 7) << 3))] = rne_bf16(W[idx]);
}

// ---------------------------------------------------------------------------
// Kernel 1: h = sigmoid(x @ W_gate + b) * (x @ W) via bf16x2 MFMA, h bf16.
// ---------------------------------------------------------------------------
__global__ __launch_bounds__(256) void mfma_gemm_gate(
    const float* __restrict__ x, const unsigned short* __restrict__ wt_sw,
    const float* __restrict__ Wg, const float* __restrict__ bg,
    __hip_bfloat16* __restrict__ h, int n_nodes)
{
    __shared__ __align__(16) char smem[65792];
    unsigned short* Ahi = (unsigned short*)smem;           // [64][128] swz, 16KB
    unsigned short* Alo = Ahi + 64 * 128;                  // 16KB
    unsigned short* Bt  = Alo + 64 * 128;                  // [128][128] swz, 32KB
    float*          Gs  = (float*)(Bt + 128 * 128);        // [64]
    unsigned short* Cbuf = (unsigned short*)smem;          // [64][136] reuse, 17KB

    const int t    = threadIdx.x;
    const int lane = t & 63;
    const int w    = t >> 6;
    const int node0 = blockIdx.x * BM;

    // ---- stage W tile: linear copy of pre-swizzled source (conflict-free)
    #pragma unroll
    for (int i = 0; i < 8; ++i) {
        int e0 = (i * 256 + t) * 8;
        *(int4*)&Bt[e0] = *(const int4*)&wt_sw[e0];
    }

    // ---- stage x tile as bf16 hi/lo, XOR-swizzled
    #pragma unroll
    for (int i = 0; i < 8; ++i) {
        int fidx = (i * 256 + t) * 4;          // flat f32 index in 64x128 tile
        int row  = fidx >> 7;
        int k    = fidx & 127;
        int node = node0 + row;
        float4 v = make_float4(0.f, 0.f, 0.f, 0.f);
        if (node < n_nodes) v = *(const float4*)(x + (size_t)node * D + k);
        unsigned short hi[4], lo[4];
        float vf[4] = {v.x, v.y, v.z, v.w};
        #pragma unroll
        for (int j = 0; j < 4; ++j) {
            hi[j] = rne_bf16(vf[j]);
            float fh = __uint_as_float((unsigned)hi[j] << 16);
            lo[j] = rne_bf16(vf[j] - fh);
        }
        int eidx = row * 128 + (k ^ ((row & 7) << 3));
        *(unsigned long long*)&Ahi[eidx] =
            (unsigned long long)hi[0] | ((unsigned long long)hi[1] << 16) |
            ((unsigned long long)hi[2] << 32) | ((unsigned long long)hi[3] << 48);
        *(unsigned long long*)&Alo[eidx] =
            (unsigned long long)lo[0] | ((unsigned long long)lo[1] << 16) |
            ((unsigned long long)lo[2] << 32) | ((unsigned long long)lo[3] << 48);
    }
    __syncthreads();

    // ---- gate (threads 0..63)
    if (t < BM) {
        float gp = 0.f;
        #pragma unroll
        for (int kq = 0; kq < 16; ++kq) {
            int eidx = t * 128 + ((kq * 8) ^ ((t & 7) << 3));
            unsigned long long a = *(const unsigned long long*)&Ahi[eidx];
            unsigned long long b = *(const unsigned long long*)&Ahi[eidx + 4];
            #pragma unroll
            for (int j = 0; j < 4; ++j) {
                gp += __uint_as_float((unsigned)((a >> (16 * j)) & 0xFFFF) << 16) * Wg[kq * 8 + j];
                gp += __uint_as_float((unsigned)((b >> (16 * j)) & 0xFFFF) << 16) * Wg[kq * 8 + 4 + j];
            }
        }
        Gs[t] = 1.f / (1.f + __expf(-(gp + bg[0])));
    }

    // ---- MFMA main loop
    f32x4 acc[4][2];
    #pragma unroll
    for (int m = 0; m < 4; ++m)
        #pragma unroll
        for (int n = 0; n < 2; ++n)
            acc[m][n] = (f32x4){0.f, 0.f, 0.f, 0.f};

    #pragma unroll
    for (int kk = 0; kk < 4; ++kk) {
        const int k0 = kk * 32 + (lane >> 4) * 8;
        bf16x8 bfr[2];
        #pragma unroll
        for (int n = 0; n < 2; ++n) {
            int f = w * 32 + n * 16 + (lane & 15);
            bfr[n] = *(const bf16x8*)&Bt[f * 128 + (k0 ^ ((f & 7) << 3))];
        }
        #pragma unroll
        for (int m = 0; m < 4; ++m) {
            int row = m * 16 + (lane & 15);
            int eidx = row * 128 + (k0 ^ ((row & 7) << 3));
            bf16x8 ah = *(const bf16x8*)&Ahi[eidx];
            bf16x8 al = *(const bf16x8*)&Alo[eidx];
            #pragma unroll
            for (int n = 0; n < 2; ++n) {
                acc[m][n] = __builtin_amdgcn_mfma_f32_16x16x32_bf16(ah, bfr[n], acc[m][n], 0, 0, 0);
                acc[m][n] = __builtin_amdgcn_mfma_f32_16x16x32_bf16(al, bfr[n], acc[m][n], 0, 0, 0);
            }
        }
    }
    __syncthreads();   // A/B LDS dead; Gs ready

    // ---- epilogue: gate-scale, cvt bf16, scatter to Cbuf [64][136]
    #pragma unroll
    for (int m = 0; m < 4; ++m) {
        #pragma unroll
        for (int n = 0; n < 2; ++n) {
            int feat = w * 32 + n * 16 + (lane & 15);
            #pragma unroll
            for (int j = 0; j < 4; ++j) {
                int rloc = m * 16 + (lane >> 4) * 4 + j;
                Cbuf[rloc * 136 + feat] = rne_bf16(acc[m][n][j] * Gs[rloc]);
            }
        }
    }
    __syncthreads();

    // ---- coalesced store
    {
        int row  = t >> 2;
        int fb   = (t & 3) * 32;
        int node = node0 + row;
        if (node < n_nodes) {
            __hip_bfloat16* hp = h + (size_t)node * D + fb;
            #pragma unroll
            for (int q = 0; q < 4; ++q)
                *(int4*)(hp + q * 8) = *(const int4*)&Cbuf[row * 136 + fb + q * 8];
        }
    }
}

// ---------------------------------------------------------------------------
// Bucket histogram (128-row buckets) via LDS, merged with global atomics.
// ---------------------------------------------------------------------------
__global__ __launch_bounds__(256) void hist_bkt(
    const int* __restrict__ er, int* __restrict__ cntb, int n_edges)
{
    __shared__ int lh[NBKT_PAD];
    const int t = threadIdx.x;
    for (int i = t; i < NBKT_PAD; i += 256) lh[i] = 0;
    __syncthreads();
    const int e0 = blockIdx.x * CHUNK;
    const int ecnt = min(CHUNK, n_edges - e0);
    for (int i = t; i < ecnt; i += 256) atomicAdd(&lh[er[e0 + i] >> 7], 1);
    __syncthreads();
    for (int i = t; i < NBKT_PAD; i += 256) {
        int v = lh[i];
        if (v) atomicAdd(&cntb[i], v);
    }
}

// ---------------------------------------------------------------------------
// Single-block exclusive scan of 1024 bucket counts; zeroes gcursor.
// ---------------------------------------------------------------------------
__global__ __launch_bounds__(256) void scan_bkt(
    const int* __restrict__ cntb, int* __restrict__ bktStart,
    int* __restrict__ gcursor)
{
    __shared__ int wtot[4];
    const int t = threadIdx.x, lane = t & 63, w = t >> 6;
    const int base = t * 4;
    int v[4], tsum = 0;
    #pragma unroll
    for (int j = 0; j < 4; ++j) { v[j] = cntb[base + j]; tsum += v[j]; }
    int x = tsum;
    #pragma unroll
    for (int d = 1; d < 64; d <<= 1) {
        int y = __shfl_up(x, d);
        if (lane >= d) x += y;
    }
    if (lane == 63) wtot[w] = x;
    __syncthreads();
    int woff = 0;
    for (int i = 0; i < w; ++i) woff += wtot[i];
    int run = woff + x - tsum;
    #pragma unroll
    for (int j = 0; j < 4; ++j) { bktStart[base + j] = run; run += v[j]; }
    if (t == 255) bktStart[NBKT_PAD] = run;
    #pragma unroll
    for (int j = 0; j < 4; ++j) gcursor[base + j] = 0;
}

// ---------------------------------------------------------------------------
// Bin edges into 128-row buckets via LDS staging (coalesced bucket runs).
// Entry: {packed = col | (row&127)<<17, val_bits}. col < 2^17 (N=100k).
// ---------------------------------------------------------------------------
__global__ __launch_bounds__(256) void bin_pass(
    const int* __restrict__ er, const int* __restrict__ ec,
    const float* __restrict__ ev, const int* __restrict__ bktStart,
    int* __restrict__ gcursor, uint2* __restrict__ bucketArr, int n_edges)
{
    __shared__ uint2 staged[CHUNK];            // 32 KB
    __shared__ unsigned short bkt_of[CHUNK];   // 8 KB
    __shared__ int lcnt[NBKT_PAD];             // 4 KB each
    __shared__ int lbase[NBKT_PAD];
    __shared__ int gbase[NBKT_PAD];
    __shared__ int wt[4];

    const int t = threadIdx.x;
    const int lane = t & 63, w = t >> 6;
    const int e0 = blockIdx.x * CHUNK;
    const int ecnt = min(CHUNK, n_edges - e0);

    for (int i = t; i < NBKT_PAD; i += 256) lcnt[i] = 0;
    __syncthreads();

    for (int i = t; i < ecnt; i += 256) atomicAdd(&lcnt[er[e0 + i] >> 7], 1);
    __syncthreads();

    {   // exclusive scan of 1024 counters (4 per thread); reset lcnt as cursor
        const int base = t * 4;
        int v[4], tsum = 0;
        #pragma unroll
        for (int j = 0; j < 4; ++j) { v[j] = lcnt[base + j]; tsum += v[j]; }
        int x = tsum;
        #pragma unroll
        for (int d = 1; d < 64; d <<= 1) {
            int y = __shfl_up(x, d);
            if (lane >= d) x += y;
        }
        if (lane == 63) wt[w] = x;
        __syncthreads();
        int woff = 0;
        for (int i = 0; i < w; ++i) woff += wt[i];
        int run = woff + x - tsum;
        #pragma unroll
        for (int j = 0; j < 4; ++j) { lbase[base + j] = run; run += v[j]; lcnt[base + j] = 0; }
    }
    __syncthreads();

    // scatter into LDS, bucket-grouped
    for (int i = t; i < ecnt; i += 256) {
        int r = er[e0 + i];
        int b = r >> 7;
        int p = lbase[b] + atomicAdd(&lcnt[b], 1);
        staged[p] = make_uint2((unsigned)ec[e0 + i] | ((unsigned)(r & 127) << 17),
                               (unsigned)__float_as_int(ev[e0 + i]));
        bkt_of[p] = (unsigned short)b;
    }
    __syncthreads();

    // reserve global space per bucket
    for (int i = t; i < NBKT_PAD; i += 256) {
        int c = lcnt[i];
        if (c) gbase[i] = bktStart[i] + atomicAdd(&gcursor[i], c);
    }
    __syncthreads();

    // bulk copy: contiguous LDS runs -> per-bucket global regions
    for (int i = t; i < ecnt; i += 256) {
        int b = bkt_of[i];
        bucketArr[gbase[b] + (i - lbase[b])] = staged[i];
    }
}

// ---------------------------------------------------------------------------
// Fused sort + gather: per 128-row bucket, build row-sorted edge list in LDS
// (hist -> scan -> scatter; never written back to global), then gather:
// wave w handles rows w+4k; 8 h-loads in flight; shfl-reduce; coalesced out.
// ---------------------------------------------------------------------------
__global__ __launch_bounds__(256) void sort_gather(
    const int* __restrict__ bktStart, const uint2* __restrict__ bucketArr,
    const __hip_bfloat16* __restrict__ h, float* __restrict__ out, int n_nodes)
{
    __shared__ uint2 sEdges[BKT_CAP];   // 24 KB
    __shared__ int rcnt[128];
    __shared__ int rbase[129];
    __shared__ int rfill[128];
    __shared__ int wt2[2];

    const int t = threadIdx.x, lane = t & 63, w = t >> 6;
    const int b = blockIdx.x;
    const int r0 = b << 7;
    const int s = bktStart[b];
    const int e = bktStart[b + 1];
    const int cnt = e - s;
    const bool ovf = cnt > BKT_CAP;     // 22-sigma event; filtered-global fallback

    if (t < 128) rcnt[t] = 0;
    __syncthreads();

    if (!ovf) {
        for (int i = t; i < cnt; i += 256)
            atomicAdd(&rcnt[(bucketArr[s + i].x >> 17) & 127], 1);
    }
    __syncthreads();

    // exclusive scan of 128 row counts (waves 0,1)
    {
        int v = 0, x = 0;
        if (t < 128) {
            v = rcnt[t];
            x = v;
            #pragma unroll
            for (int d = 1; d < 64; d <<= 1) {
                int y = __shfl_up(x, d);
                if (lane >= d) x += y;
            }
            if (lane == 63) wt2[w] = x;
        }
        __syncthreads();
        if (t < 128) {
            int rb = (w ? wt2[0] : 0) + x - v;
            rbase[t] = rb;
            rfill[t] = rb;
        }
        if (t == 0) rbase[128] = cnt;
    }
    __syncthreads();

    if (!ovf) {
        for (int i = t; i < cnt; i += 256) {
            uint2 pe = bucketArr[s + i];
            int rl = (pe.x >> 17) & 127;
            int p  = atomicAdd(&rfill[rl], 1);
            sEdges[p] = pe;
        }
    }
    __syncthreads();

    // ---- gather phase: wave w -> rows rl = w + 4k
    const int g = lane >> 4;            // edge slot group 0..3
    const int p = lane & 15;            // feat block (8 feats)

    for (int k = 0; k < 32; ++k) {
        const int rl = w + (k << 2);
        const int row = r0 + rl;
        if (row >= n_nodes) continue;

        float acc[8];
        #pragma unroll
        for (int j = 0; j < 8; ++j) acc[j] = 0.f;

        if (!ovf) {
            const int rs = rbase[rl], re = rbase[rl + 1];
            for (int bb = rs; bb < re; bb += 8) {
                int i0 = bb + g;
                int i1 = i0 + 4;
                float v0 = 0.f, v1 = 0.f;
                int c0 = 0, c1 = 0;
                if (i0 < re) { uint2 pk = sEdges[i0]; v0 = __uint_as_float(pk.y); c0 = (int)(pk.x & 0x1FFFFu); }
                if (i1 < re) { uint2 pk = sEdges[i1]; v1 = __uint_as_float(pk.y); c1 = (int)(pk.x & 0x1FFFFu); }
                const int4 h0 = *(const int4*)(h + (size_t)c0 * D + p * 8);
                const int4 h1 = *(const int4*)(h + (size_t)c1 * D + p * 8);
                {
                    unsigned d0 = (unsigned)h0.x, d1 = (unsigned)h0.y, d2 = (unsigned)h0.z, d3 = (unsigned)h0.w;
                    acc[0] += v0 * __uint_as_float(d0 << 16);
                    acc[1] += v0 * __uint_as_float(d0 & 0xFFFF0000u);
                    acc[2] += v0 * __uint_as_float(d1 << 16);
                    acc[3] += v0 * __uint_as_float(d1 & 0xFFFF0000u);
                    acc[4] += v0 * __uint_as_float(d2 << 16);
                    acc[5] += v0 * __uint_as_float(d2 & 0xFFFF0000u);
                    acc[6] += v0 * __uint_as_float(d3 << 16);
                    acc[7] += v0 * __uint_as_float(d3 & 0xFFFF0000u);
                }
                {
                    unsigned d0 = (unsigned)h1.x, d1 = (unsigned)h1.y, d2 = (unsigned)h1.z, d3 = (unsigned)h1.w;
                    acc[0] += v1 * __uint_as_float(d0 << 16);
                    acc[1] += v1 * __uint_as_float(d0 & 0xFFFF0000u);
                    acc[2] += v1 * __uint_as_float(d1 << 16);
                    acc[3] += v1 * __uint_as_float(d1 & 0xFFFF0000u);
                    acc[4] += v1 * __uint_as_float(d2 << 16);
                    acc[5] += v1 * __uint_as_float(d2 & 0xFFFF0000u);
                    acc[6] += v1 * __uint_as_float(d3 << 16);
                    acc[7] += v1 * __uint_as_float(d3 & 0xFFFF0000u);
                }
            }
        } else {
            // filtered scan of the whole (unsorted) global segment
            const unsigned target = (unsigned)rl;
            for (int bb = 0; bb < cnt; bb += 8) {
                int i0 = bb + g;
                int i1 = i0 + 4;
                float v0 = 0.f, v1 = 0.f;
                int c0 = 0, c1 = 0;
                if (i0 < cnt) {
                    uint2 pk = bucketArr[s + i0];
                    if (((pk.x >> 17) & 127u) == target) { v0 = __uint_as_float(pk.y); c0 = (int)(pk.x & 0x1FFFFu); }
                }
                if (i1 < cnt) {
                    uint2 pk = bucketArr[s + i1];
                    if (((pk.x >> 17) & 127u) == target) { v1 = __uint_as_float(pk.y); c1 = (int)(pk.x & 0x1FFFFu); }
                }
                const int4 h0 = *(const int4*)(h + (size_t)c0 * D + p * 8);
                const int4 h1 = *(const int4*)(h + (size_t)c1 * D + p * 8);
                {
                    unsigned d0 = (unsigned)h0.x, d1 = (unsigned)h0.y, d2 = (unsigned)h0.z, d3 = (unsigned)h0.w;
                    acc[0] += v0 * __uint_as_float(d0 << 16);
                    acc[1] += v0 * __uint_as_float(d0 & 0xFFFF0000u);
                    acc[2] += v0 * __uint_as_float(d1 << 16);
                    acc[3] += v0 * __uint_as_float(d1 & 0xFFFF0000u);
                    acc[4] += v0 * __uint_as_float(d2 << 16);
                    acc[5] += v0 * __uint_as_float(d2 & 0xFFFF0000u);
                    acc[6] += v0 * __uint_as_float(d3 << 16);
                    acc[7] += v0 * __uint_as_float(d3 & 0xFFFF0000u);
                }
                {
                    unsigned d0 = (unsigned)h1.x, d1 = (unsigned)h1.y, d2 = (unsigned)h1.z, d3 = (unsigned)h1.w;
                    acc[0] += v1 * __uint_as_float(d0 << 16);
                    acc[1] += v1 * __uint_as_float(d0 & 0xFFFF0000u);
                    acc[2] += v1 * __uint_as_float(d1 << 16);
                    acc[3] += v1 * __uint_as_float(d1 & 0xFFFF0000u);
                    acc[4] += v1 * __uint_as_float(d2 << 16);
                    acc[5] += v1 * __uint_as_float(d2 & 0xFFFF0000u);
                    acc[6] += v1 * __uint_as_float(d3 << 16);
                    acc[7] += v1 * __uint_as_float(d3 & 0xFFFF0000u);
                }
            }
        }

        // reduce across the 4 edge groups (lane bits 4,5)
        #pragma unroll
        for (int j = 0; j < 8; ++j) {
            acc[j] += __shfl_xor(acc[j], 16);
            acc[j] += __shfl_xor(acc[j], 32);
        }

        if (lane < 16) {
            float* op = out + (size_t)row * D + lane * 8;
            *(float4*)(op)     = make_float4(acc[0], acc[1], acc[2], acc[3]);
            *(float4*)(op + 4) = make_float4(acc[4], acc[5], acc[6], acc[7]);
        }
    }
}

// ---------------------------------------------------------------------------
// Fallback (ws too small): atomic scatter
// ---------------------------------------------------------------------------
__global__ __launch_bounds__(256) void scatter_edges(
    const int* __restrict__ er, const int* __restrict__ ec,
    const float* __restrict__ ev, const __hip_bfloat16* __restrict__ h,
    float* __restrict__ out, int n_edges)
{
    int gw   = (blockIdx.x * 256 + threadIdx.x) >> 6;
    int lane = threadIdx.x & 63;
    if (gw >= n_edges) return;
    int r = er[gw];
    int c = ec[gw];
    float v = ev[gw];
    unsigned hv = *(const unsigned*)(h + (size_t)c * D + lane * 2);
    float* op = out + (size_t)r * D + lane * 2;
    atomicAdd(op,     v * __uint_as_float(hv << 16));
    atomicAdd(op + 1, v * __uint_as_float(hv & 0xFFFF0000u));
}

extern "C" void kernel_launch(void* const* d_in, const int* in_sizes, int n_in,
                              void* d_out, int out_size, void* d_ws, size_t ws_size,
                              hipStream_t stream) {
    const float* x  = (const float*)d_in[0];
    const int*   er = (const int*)d_in[1];
    const int*   ec = (const int*)d_in[2];
    const float* ev = (const float*)d_in[3];
    const float* W  = (const float*)d_in[4];
    const float* Wg = (const float*)d_in[5];
    const float* bg = (const float*)d_in[6];
    float* out = (float*)d_out;

    const int n_nodes = in_sizes[0] / D;
    const int n_edges = in_sizes[1];
    const int nbkt = (n_nodes + 127) >> 7;   // 128-row buckets

    char* ws = (char*)d_ws;
    size_t off = 0;
    auto alloc = [&](size_t bytes) {
        char* p = ws + off;
        off += (bytes + 15) & ~size_t(15);
        return p;
    };
    __hip_bfloat16* h = (__hip_bfloat16*)alloc((size_t)n_nodes * D * sizeof(__hip_bfloat16));
    unsigned short* wt_sw = (unsigned short*)alloc((size_t)D * D * sizeof(unsigned short));
    uint2* bucketArr = (uint2*)alloc((size_t)n_edges * sizeof(uint2));
    int*   bktStart  = (int*)  alloc((NBKT_PAD + 1) * sizeof(int));
    int*   cntb      = (int*)  alloc(NBKT_PAD * sizeof(int));   // | contiguous
    int*   gcursor   = (int*)  alloc(NBKT_PAD * sizeof(int));   // | memset
    bool have_ws = off <= ws_size;

    // W -> transposed, pre-swizzled bf16
    transpose_W<<<D * D / 256, 256, 0, stream>>>(W, wt_sw);

    // h = gate(x) * (x @ W) via MFMA
    dim3 gemm_grid((n_nodes + BM - 1) / BM);
    mfma_gemm_gate<<<gemm_grid, 256, 0, stream>>>(x, wt_sw, Wg, bg, h, n_nodes);

    if (have_ws) {
        hipMemsetAsync(cntb, 0, 2 * NBKT_PAD * sizeof(int), stream);  // cntb+gcursor
        int cb = (n_edges + CHUNK - 1) / CHUNK;
        hist_bkt<<<cb, 256, 0, stream>>>(er, cntb, n_edges);
        scan_bkt<<<1, 256, 0, stream>>>(cntb, bktStart, gcursor);
        bin_pass<<<cb, 256, 0, stream>>>(er, ec, ev, bktStart, gcursor, bucketArr, n_edges);
        sort_gather<<<nbkt, 256, 0, stream>>>(bktStart, bucketArr, h, out, n_nodes);
    } else {
        hipMemsetAsync(d_out, 0, (size_t)out_size * sizeof(float), stream);
        int blocks = (n_edges + 3) / 4;
        scatter_edges<<<blocks, 256, 0, stream>>>(er, ec, ev, h, out, n_edges);
    }
}

// Round 10
// 134.104 us; speedup vs baseline: 10.5861x; 1.1727x over previous
//
#include <hip/hip_runtime.h>
#include <hip/hip_bf16.h>

constexpr int D        = 128;   // feature dim = K = UNITS
constexpr int BM       = 64;    // nodes per block in GEMM
constexpr int CHUNK    = 4096;  // edges per binning block
constexpr int NBKT_PAD = 1024;  // padded bucket count (actual = ceil(N/128) = 782)
constexpr int BKT_CAP  = 3072;  // sort_gather LDS capacity (mean 2048, sigma ~45)
constexpr int BKT_STRIDE = 4096; // fixed per-bucket region in bucketArr
constexpr int OVF_CAP  = 65536; // overflow list (never used statistically)

typedef __attribute__((ext_vector_type(8))) short bf16x8;
typedef __attribute__((ext_vector_type(4))) float f32x4;

__device__ __forceinline__ unsigned short rne_bf16(float f) {
    unsigned u = __float_as_uint(f);
    return (unsigned short)((u + 0x7FFF + ((u >> 16) & 1)) >> 16);
}

// ---------------------------------------------------------------------------
// One-time: W[k][f] f32 -> Wt_sw (transposed [f][k] bf16, XOR-pre-swizzled)
// ---------------------------------------------------------------------------
__global__ __launch_bounds__(256) void transpose_W(
    const float* __restrict__ W, unsigned short* __restrict__ wt_sw)
{
    int idx = blockIdx.x * 256 + threadIdx.x;   // 16384 elems
    int k = idx >> 7, f = idx & 127;
    wt_sw[f * 128 + (k ^ ((f & 7) << 3))] = rne_bf16(W[idx]);
}

// ---------------------------------------------------------------------------
// Kernel 1: h = sigmoid(x @ W_gate + b) * (x @ W) via bf16 MFMA, h bf16.
// Single-bf16 x (no hi/lo split): quantization error ~0.0016 on h, well under
// the bf16-h storage error already present. 48.5 KB LDS -> 3 blocks/CU.
// ---------------------------------------------------------------------------
__global__ __launch_bounds__(256) void mfma_gemm_gate(
    const float* __restrict__ x, const unsigned short* __restrict__ wt_sw,
    const float* __restrict__ Wg, const float* __restrict__ bg,
    __hip_bfloat16* __restrict__ h, int n_nodes)
{
    __shared__ __align__(16) char smem[49664];
    unsigned short* Ahi = (unsigned short*)smem;           // [64][128] swz, 16KB
    unsigned short* Bt  = Ahi + 64 * 128;                  // [128][128] swz, 32KB
    float*          Gs  = (float*)(Bt + 128 * 128);        // [64], 256B
    unsigned short* Cbuf = (unsigned short*)smem;          // [64][136] reuse, 17.4KB

    const int t    = threadIdx.x;
    const int lane = t & 63;
    const int w    = t >> 6;
    const int node0 = blockIdx.x * BM;

    // ---- stage W tile: linear copy of pre-swizzled source (conflict-free)
    #pragma unroll
    for (int i = 0; i < 8; ++i) {
        int e0 = (i * 256 + t) * 8;
        *(int4*)&Bt[e0] = *(const int4*)&wt_sw[e0];
    }

    // ---- stage x tile as bf16, XOR-swizzled
    #pragma unroll
    for (int i = 0; i < 8; ++i) {
        int fidx = (i * 256 + t) * 4;          // flat f32 index in 64x128 tile
        int row  = fidx >> 7;
        int k    = fidx & 127;
        int node = node0 + row;
        float4 v = make_float4(0.f, 0.f, 0.f, 0.f);
        if (node < n_nodes) v = *(const float4*)(x + (size_t)node * D + k);
        unsigned long long pk =
            (unsigned long long)rne_bf16(v.x) |
            ((unsigned long long)rne_bf16(v.y) << 16) |
            ((unsigned long long)rne_bf16(v.z) << 32) |
            ((unsigned long long)rne_bf16(v.w) << 48);
        int eidx = row * 128 + (k ^ ((row & 7) << 3));
        *(unsigned long long*)&Ahi[eidx] = pk;
    }
    __syncthreads();

    // ---- gate (threads 0..63)
    if (t < BM) {
        float gp = 0.f;
        #pragma unroll
        for (int kq = 0; kq < 16; ++kq) {
            int eidx = t * 128 + ((kq * 8) ^ ((t & 7) << 3));
            unsigned long long a = *(const unsigned long long*)&Ahi[eidx];
            unsigned long long b = *(const unsigned long long*)&Ahi[eidx + 4];
            #pragma unroll
            for (int j = 0; j < 4; ++j) {
                gp += __uint_as_float((unsigned)((a >> (16 * j)) & 0xFFFF) << 16) * Wg[kq * 8 + j];
                gp += __uint_as_float((unsigned)((b >> (16 * j)) & 0xFFFF) << 16) * Wg[kq * 8 + 4 + j];
            }
        }
        Gs[t] = 1.f / (1.f + __expf(-(gp + bg[0])));
    }

    // ---- MFMA main loop (32 MFMAs)
    f32x4 acc[4][2];
    #pragma unroll
    for (int m = 0; m < 4; ++m)
        #pragma unroll
        for (int n = 0; n < 2; ++n)
            acc[m][n] = (f32x4){0.f, 0.f, 0.f, 0.f};

    #pragma unroll
    for (int kk = 0; kk < 4; ++kk) {
        const int k0 = kk * 32 + (lane >> 4) * 8;
        bf16x8 bfr[2];
        #pragma unroll
        for (int n = 0; n < 2; ++n) {
            int f = w * 32 + n * 16 + (lane & 15);
            bfr[n] = *(const bf16x8*)&Bt[f * 128 + (k0 ^ ((f & 7) << 3))];
        }
        #pragma unroll
        for (int m = 0; m < 4; ++m) {
            int row = m * 16 + (lane & 15);
            bf16x8 ah = *(const bf16x8*)&Ahi[row * 128 + (k0 ^ ((row & 7) << 3))];
            #pragma unroll
            for (int n = 0; n < 2; ++n)
                acc[m][n] = __builtin_amdgcn_mfma_f32_16x16x32_bf16(ah, bfr[n], acc[m][n], 0, 0, 0);
        }
    }
    __syncthreads();   // A/B LDS dead; Gs ready

    // ---- epilogue: gate-scale, cvt bf16, scatter to Cbuf [64][136]
    #pragma unroll
    for (int m = 0; m < 4; ++m) {
        #pragma unroll
        for (int n = 0; n < 2; ++n) {
            int feat = w * 32 + n * 16 + (lane & 15);
            #pragma unroll
            for (int j = 0; j < 4; ++j) {
                int rloc = m * 16 + (lane >> 4) * 4 + j;
                Cbuf[rloc * 136 + feat] = rne_bf16(acc[m][n][j] * Gs[rloc]);
            }
        }
    }
    __syncthreads();

    // ---- coalesced store
    {
        int row  = t >> 2;
        int fb   = (t & 3) * 32;
        int node = node0 + row;
        if (node < n_nodes) {
            __hip_bfloat16* hp = h + (size_t)node * D + fb;
            #pragma unroll
            for (int q = 0; q < 4; ++q)
                *(int4*)(hp + q * 8) = *(const int4*)&Cbuf[row * 136 + fb + q * 8];
        }
    }
}

// ---------------------------------------------------------------------------
// Bin edges into 128-row buckets via LDS staging. Fixed-stride bucket regions
// (no global histogram/scan needed): base = atomicAdd(gcursor[b], count).
// Entry: {packed = col | (row&127)<<17, val_bits}. col < 2^17 (N=100k).
// Overflow beyond BKT_STRIDE goes to a tiny global list (statistically never).
// ---------------------------------------------------------------------------
__global__ __launch_bounds__(256) void bin_pass(
    const int* __restrict__ er, const int* __restrict__ ec,
    const float* __restrict__ ev, int* __restrict__ gcursor,
    uint2* __restrict__ bucketArr, int* __restrict__ ovfCur,
    uint4* __restrict__ ovfArr, int n_edges)
{
    __shared__ uint2 staged[CHUNK];            // 32 KB
    __shared__ unsigned short bkt_of[CHUNK];   // 8 KB
    __shared__ int lcnt[NBKT_PAD];             // 4 KB each
    __shared__ int lbase[NBKT_PAD];
    __shared__ int gbase[NBKT_PAD];
    __shared__ int wt[4];

    const int t = threadIdx.x;
    const int lane = t & 63, w = t >> 6;
    const int e0 = blockIdx.x * CHUNK;
    const int ecnt = min(CHUNK, n_edges - e0);

    for (int i = t; i < NBKT_PAD; i += 256) lcnt[i] = 0;
    __syncthreads();

    for (int i = t; i < ecnt; i += 256) atomicAdd(&lcnt[er[e0 + i] >> 7], 1);
    __syncthreads();

    {   // exclusive scan of 1024 counters (4 per thread); reset lcnt as cursor
        const int base = t * 4;
        int v[4], tsum = 0;
        #pragma unroll
        for (int j = 0; j < 4; ++j) { v[j] = lcnt[base + j]; tsum += v[j]; }
        int x = tsum;
        #pragma unroll
        for (int d = 1; d < 64; d <<= 1) {
            int y = __shfl_up(x, d);
            if (lane >= d) x += y;
        }
        if (lane == 63) wt[w] = x;
        __syncthreads();
        int woff = 0;
        for (int i = 0; i < w; ++i) woff += wt[i];
        int run = woff + x - tsum;
        #pragma unroll
        for (int j = 0; j < 4; ++j) { lbase[base + j] = run; run += v[j]; lcnt[base + j] = 0; }
    }
    __syncthreads();

    // scatter into LDS, bucket-grouped
    for (int i = t; i < ecnt; i += 256) {
        int r = er[e0 + i];
        int b = r >> 7;
        int p = lbase[b] + atomicAdd(&lcnt[b], 1);
        staged[p] = make_uint2((unsigned)ec[e0 + i] | ((unsigned)(r & 127) << 17),
                               (unsigned)__float_as_int(ev[e0 + i]));
        bkt_of[p] = (unsigned short)b;
    }
    __syncthreads();

    // reserve global space per bucket (fixed-stride regions)
    for (int i = t; i < NBKT_PAD; i += 256) {
        int c = lcnt[i];
        if (c) gbase[i] = atomicAdd(&gcursor[i], c);
    }
    __syncthreads();

    // bulk copy: contiguous LDS runs -> per-bucket global regions
    for (int i = t; i < ecnt; i += 256) {
        int b = bkt_of[i];
        int pos = gbase[b] + (i - lbase[b]);
        uint2 pe = staged[i];
        if (pos < BKT_STRIDE) {
            bucketArr[(size_t)b * BKT_STRIDE + pos] = pe;
        } else {
            int op = atomicAdd(ovfCur, 1);
            if (op < OVF_CAP) ovfArr[op] = make_uint4((unsigned)b, pe.x, pe.y, 0u);
        }
    }
}

// ---------------------------------------------------------------------------
// Fused sort + gather: per 128-row bucket, build row-sorted edge list in LDS,
// then gather: wave w handles rows w+4k; 8 h-loads in flight; shfl-reduce.
// ---------------------------------------------------------------------------
__global__ __launch_bounds__(256) void sort_gather(
    const int* __restrict__ gcursor, const uint2* __restrict__ bucketArr,
    const int* __restrict__ ovfCur, const uint4* __restrict__ ovfArr,
    const __hip_bfloat16* __restrict__ h, float* __restrict__ out, int n_nodes)
{
    __shared__ uint2 sEdges[BKT_CAP];   // 24 KB
    __shared__ int rcnt[128];
    __shared__ int rbase[129];
    __shared__ int rfill[128];
    __shared__ int wt2[2];

    const int t = threadIdx.x, lane = t & 63, w = t >> 6;
    const int b = blockIdx.x;
    const int r0 = b << 7;
    const size_t s = (size_t)b * BKT_STRIDE;
    const int total = gcursor[b];
    const int cnt = min(total, BKT_STRIDE);
    const bool ovf = cnt > BKT_CAP;     // LDS-sort overflow: filtered-global path
    const int ovfN = (total > BKT_STRIDE || *ovfCur > 0) ? min(*ovfCur, OVF_CAP) : 0;

    if (t < 128) rcnt[t] = 0;
    __syncthreads();

    if (!ovf) {
        for (int i = t; i < cnt; i += 256)
            atomicAdd(&rcnt[(bucketArr[s + i].x >> 17) & 127], 1);
    }
    __syncthreads();

    // exclusive scan of 128 row counts (waves 0,1)
    {
        int v = 0, x = 0;
        if (t < 128) {
            v = rcnt[t];
            x = v;
            #pragma unroll
            for (int d = 1; d < 64; d <<= 1) {
                int y = __shfl_up(x, d);
                if (lane >= d) x += y;
            }
            if (lane == 63) wt2[w] = x;
        }
        __syncthreads();
        if (t < 128) {
            int rb = (w ? wt2[0] : 0) + x - v;
            rbase[t] = rb;
            rfill[t] = rb;
        }
        if (t == 0) rbase[128] = cnt;
    }
    __syncthreads();

    if (!ovf) {
        for (int i = t; i < cnt; i += 256) {
            uint2 pe = bucketArr[s + i];
            int rl = (pe.x >> 17) & 127;
            int p  = atomicAdd(&rfill[rl], 1);
            sEdges[p] = pe;
        }
    }
    __syncthreads();

    // ---- gather phase: wave w -> rows rl = w + 4k
    const int g = lane >> 4;            // edge slot group 0..3
    const int p = lane & 15;            // feat block (8 feats)

    for (int k = 0; k < 32; ++k) {
        const int rl = w + (k << 2);
        const int row = r0 + rl;
        if (row >= n_nodes) continue;

        float acc[8];
        #pragma unroll
        for (int j = 0; j < 8; ++j) acc[j] = 0.f;

        if (!ovf) {
            const int rs = rbase[rl], re = rbase[rl + 1];
            for (int bb = rs; bb < re; bb += 8) {
                int i0 = bb + g;
                int i1 = i0 + 4;
                float v0 = 0.f, v1 = 0.f;
                int c0 = 0, c1 = 0;
                if (i0 < re) { uint2 pk = sEdges[i0]; v0 = __uint_as_float(pk.y); c0 = (int)(pk.x & 0x1FFFFu); }
                if (i1 < re) { uint2 pk = sEdges[i1]; v1 = __uint_as_float(pk.y); c1 = (int)(pk.x & 0x1FFFFu); }
                const int4 h0 = *(const int4*)(h + (size_t)c0 * D + p * 8);
                const int4 h1 = *(const int4*)(h + (size_t)c1 * D + p * 8);
                {
                    unsigned d0 = (unsigned)h0.x, d1 = (unsigned)h0.y, d2 = (unsigned)h0.z, d3 = (unsigned)h0.w;
                    acc[0] += v0 * __uint_as_float(d0 << 16);
                    acc[1] += v0 * __uint_as_float(d0 & 0xFFFF0000u);
                    acc[2] += v0 * __uint_as_float(d1 << 16);
                    acc[3] += v0 * __uint_as_float(d1 & 0xFFFF0000u);
                    acc[4] += v0 * __uint_as_float(d2 << 16);
                    acc[5] += v0 * __uint_as_float(d2 & 0xFFFF0000u);
                    acc[6] += v0 * __uint_as_float(d3 << 16);
                    acc[7] += v0 * __uint_as_float(d3 & 0xFFFF0000u);
                }
                {
                    unsigned d0 = (unsigned)h1.x, d1 = (unsigned)h1.y, d2 = (unsigned)h1.z, d3 = (unsigned)h1.w;
                    acc[0] += v1 * __uint_as_float(d0 << 16);
                    acc[1] += v1 * __uint_as_float(d0 & 0xFFFF0000u);
                    acc[2] += v1 * __uint_as_float(d1 << 16);
                    acc[3] += v1 * __uint_as_float(d1 & 0xFFFF0000u);
                    acc[4] += v1 * __uint_as_float(d2 << 16);
                    acc[5] += v1 * __uint_as_float(d2 & 0xFFFF0000u);
                    acc[6] += v1 * __uint_as_float(d3 << 16);
                    acc[7] += v1 * __uint_as_float(d3 & 0xFFFF0000u);
                }
            }
        } else {
            // filtered scan of the whole (unsorted) global segment
            const unsigned target = (unsigned)rl;
            for (int bb = 0; bb < cnt; bb += 8) {
                int i0 = bb + g;
                int i1 = i0 + 4;
                float v0 = 0.f, v1 = 0.f;
                int c0 = 0, c1 = 0;
                if (i0 < cnt) {
                    uint2 pk = bucketArr[s + i0];
                    if (((pk.x >> 17) & 127u) == target) { v0 = __uint_as_float(pk.y); c0 = (int)(pk.x & 0x1FFFFu); }
                }
                if (i1 < cnt) {
                    uint2 pk = bucketArr[s + i1];
                    if (((pk.x >> 17) & 127u) == target) { v1 = __uint_as_float(pk.y); c1 = (int)(pk.x & 0x1FFFFu); }
                }
                const int4 h0 = *(const int4*)(h + (size_t)c0 * D + p * 8);
                const int4 h1 = *(const int4*)(h + (size_t)c1 * D + p * 8);
                {
                    unsigned d0 = (unsigned)h0.x, d1 = (unsigned)h0.y, d2 = (unsigned)h0.z, d3 = (unsigned)h0.w;
                    acc[0] += v0 * __uint_as_float(d0 << 16);
                    acc[1] += v0 * __uint_as_float(d0 & 0xFFFF0000u);
                    acc[2] += v0 * __uint_as_float(d1 << 16);
                    acc[3] += v0 * __uint_as_float(d1 & 0xFFFF0000u);
                    acc[4] += v0 * __uint_as_float(d2 << 16);
                    acc[5] += v0 * __uint_as_float(d2 & 0xFFFF0000u);
                    acc[6] += v0 * __uint_as_float(d3 << 16);
                    acc[7] += v0 * __uint_as_float(d3 & 0xFFFF0000u);
                }
                {
                    unsigned d0 = (unsigned)h1.x, d1 = (unsigned)h1.y, d2 = (unsigned)h1.z, d3 = (unsigned)h1.w;
                    acc[0] += v1 * __uint_as_float(d0 << 16);
                    acc[1] += v1 * __uint_as_float(d0 & 0xFFFF0000u);
                    acc[2] += v1 * __uint_as_float(d1 << 16);
                    acc[3] += v1 * __uint_as_float(d1 & 0xFFFF0000u);
                    acc[4] += v1 * __uint_as_float(d2 << 16);
                    acc[5] += v1 * __uint_as_float(d2 & 0xFFFF0000u);
                    acc[6] += v1 * __uint_as_float(d3 << 16);
                    acc[7] += v1 * __uint_as_float(d3 & 0xFFFF0000u);
                }
            }
        }

        // overflow-list stragglers (rare path; group 0 only so reduce stays correct)
        if (ovfN > 0 && g == 0) {
            for (int j = 0; j < ovfN; ++j) {
                uint4 oe = ovfArr[j];
                if (oe.x == (unsigned)b && ((oe.y >> 17) & 127u) == (unsigned)rl) {
                    float v = __uint_as_float(oe.z);
                    int col = (int)(oe.y & 0x1FFFFu);
                    const int4 hv = *(const int4*)(h + (size_t)col * D + p * 8);
                    unsigned d0 = (unsigned)hv.x, d1 = (unsigned)hv.y, d2 = (unsigned)hv.z, d3 = (unsigned)hv.w;
                    acc[0] += v * __uint_as_float(d0 << 16);
                    acc[1] += v * __uint_as_float(d0 & 0xFFFF0000u);
                    acc[2] += v * __uint_as_float(d1 << 16);
                    acc[3] += v * __uint_as_float(d1 & 0xFFFF0000u);
                    acc[4] += v * __uint_as_float(d2 << 16);
                    acc[5] += v * __uint_as_float(d2 & 0xFFFF0000u);
                    acc[6] += v * __uint_as_float(d3 << 16);
                    acc[7] += v * __uint_as_float(d3 & 0xFFFF0000u);
                }
            }
        }

        // reduce across the 4 edge groups (lane bits 4,5)
        #pragma unroll
        for (int j = 0; j < 8; ++j) {
            acc[j] += __shfl_xor(acc[j], 16);
            acc[j] += __shfl_xor(acc[j], 32);
        }

        if (lane < 16) {
            float* op = out + (size_t)row * D + lane * 8;
            *(float4*)(op)     = make_float4(acc[0], acc[1], acc[2], acc[3]);
            *(float4*)(op + 4) = make_float4(acc[4], acc[5], acc[6], acc[7]);
        }
    }
}

// ---------------------------------------------------------------------------
// Fallback (ws too small): atomic scatter
// ---------------------------------------------------------------------------
__global__ __launch_bounds__(256) void scatter_edges(
    const int* __restrict__ er, const int* __restrict__ ec,
    const float* __restrict__ ev, const __hip_bfloat16* __restrict__ h,
    float* __restrict__ out, int n_edges)
{
    int gw   = (blockIdx.x * 256 + threadIdx.x) >> 6;
    int lane = threadIdx.x & 63;
    if (gw >= n_edges) return;
    int r = er[gw];
    int c = ec[gw];
    float v = ev[gw];
    unsigned hv = *(const unsigned*)(h + (size_t)c * D + lane * 2);
    float* op = out + (size_t)r * D + lane * 2;
    atomicAdd(op,     v * __uint_as_float(hv << 16));
    atomicAdd(op + 1, v * __uint_as_float(hv & 0xFFFF0000u));
}

extern "C" void kernel_launch(void* const* d_in, const int* in_sizes, int n_in,
                              void* d_out, int out_size, void* d_ws, size_t ws_size,
                              hipStream_t stream) {
    const float* x  = (const float*)d_in[0];
    const int*   er = (const int*)d_in[1];
    const int*   ec = (const int*)d_in[2];
    const float* ev = (const float*)d_in[3];
    const float* W  = (const float*)d_in[4];
    const float* Wg = (const float*)d_in[5];
    const float* bg = (const float*)d_in[6];
    float* out = (float*)d_out;

    const int n_nodes = in_sizes[0] / D;
    const int n_edges = in_sizes[1];
    const int nbkt = (n_nodes + 127) >> 7;   // 128-row buckets

    char* ws = (char*)d_ws;
    size_t off = 0;
    auto alloc = [&](size_t bytes) {
        char* p = ws + off;
        off += (bytes + 15) & ~size_t(15);
        return p;
    };
    __hip_bfloat16* h = (__hip_bfloat16*)alloc((size_t)n_nodes * D * sizeof(__hip_bfloat16));
    unsigned short* wt_sw = (unsigned short*)alloc((size_t)D * D * sizeof(unsigned short));
    uint2* bucketArr = (uint2*)alloc((size_t)nbkt * BKT_STRIDE * sizeof(uint2));
    int*   gcursor   = (int*)  alloc(NBKT_PAD * sizeof(int));   // | contiguous
    int*   ovfCur    = (int*)  alloc(16);                       // | memset
    uint4* ovfArr    = (uint4*)alloc((size_t)OVF_CAP * sizeof(uint4));
    bool have_ws = off <= ws_size;

    // W -> transposed, pre-swizzled bf16
    transpose_W<<<D * D / 256, 256, 0, stream>>>(W, wt_sw);

    // h = gate(x) * (x @ W) via MFMA
    dim3 gemm_grid((n_nodes + BM - 1) / BM);
    mfma_gemm_gate<<<gemm_grid, 256, 0, stream>>>(x, wt_sw, Wg, bg, h, n_nodes);

    if (have_ws) {
        hipMemsetAsync(gcursor, 0, NBKT_PAD * sizeof(int) + 16, stream);  // gcursor+ovfCur
        int cb = (n_edges + CHUNK - 1) / CHUNK;
        bin_pass<<<cb, 256, 0, stream>>>(er, ec, ev, gcursor, bucketArr, ovfCur, ovfArr, n_edges);
        sort_gather<<<nbkt, 256, 0, stream>>>(gcursor, bucketArr, ovfCur, ovfArr, h, out, n_nodes);
    } else {
        hipMemsetAsync(d_out, 0, (size_t)out_size * sizeof(float), stream);
        int blocks = (n_edges + 3) / 4;
        scatter_edges<<<blocks, 256, 0, stream>>>(er, ec, ev, h, out, n_edges);
    }
}